// Round 8
// baseline (258.942 us; speedup 1.0000x reference)
//
#include <hip/hip_runtime.h>
#include <stdint.h>

typedef unsigned short u16;
typedef unsigned int   u32;
typedef __attribute__((ext_vector_type(8))) short bf16x8;
typedef __attribute__((ext_vector_type(4))) float f32x4;

__device__ __forceinline__ u16 f2bf(float f) {
    union { float f; u32 u; } v; v.f = f;
    return (u16)((v.u + 0x7FFFu + ((v.u >> 16) & 1u)) >> 16);  // RNE
}
__device__ __forceinline__ float bf2f(u16 h) {
    union { u32 u; float f; } v; v.u = ((u32)h) << 16; return v.f;
}
__device__ __forceinline__ u32 fbits(float f) {
    union { float f; u32 u; } v; v.f = f; return v.u;
}

__device__ __forceinline__ void async16(const u16* g, u16* l) {
    typedef __attribute__((address_space(1))) const u32 gq;
    typedef __attribute__((address_space(3))) u32 lq;
    __builtin_amdgcn_global_load_lds((gq*)g, (lq*)l, 16, 0, 0);
}

// ---------------------------------------------------------------------------
// Prep (fused): blocks 0..10239 concat+convert x rows; 10240.. weight tiles.
// ---------------------------------------------------------------------------
__global__ void cvt_all_k(const float* __restrict__ xo, const float* __restrict__ xc,
                          u16* __restrict__ Xc,
                          const float* __restrict__ Wq, const float* __restrict__ Wkv,
                          const float* __restrict__ Wp,
                          u16* __restrict__ Wqt, u16* __restrict__ Wkt,
                          u16* __restrict__ Wpt)
{
    __shared__ __align__(16) u16 Ts[64][72];
    int id = blockIdx.x, t = threadIdx.x;
    if (id < 10240) {
        int row = id, cid = t * 4;
        int b = row >= 5120, s = row - b * 5120;
        const float* src = (s < 1024)
            ? xo + ((size_t)(b * 1024 + s)) * 1024 + cid
            : xc + ((size_t)(b * 4096 + s - 1024)) * 1024 + cid;
        float4 f = *(const float4*)src;
        union { u16 a[4]; uint2 v; } p;
        p.a[0]=f2bf(f.x); p.a[1]=f2bf(f.y); p.a[2]=f2bf(f.z); p.a[3]=f2bf(f.w);
        *(uint2*)(Xc + (size_t)row * 1024 + cid) = p.v;
        return;
    }
    int wid = id - 10240;
    const float* W; u16* Wt; int N, tile;
    if (wid < 256)      { W = Wq;  Wt = Wqt; N = 1024; tile = wid; }
    else if (wid < 768) { W = Wkv; Wt = Wkt; N = 2048; tile = wid - 256; }
    else                { W = Wp;  Wt = Wpt; N = 1024; tile = wid - 768; }
    int nt = N >> 6;
    int n0 = (tile % nt) * 64, k0 = (tile / nt) * 64;
    int lr = t >> 2, lc = (t & 3) * 16;
    const float* src = W + (size_t)(k0 + lr) * N + n0 + lc;
    union { u16 a[8]; uint4 v; } p0, p1;
    float4 f0 = *(const float4*)(src),      f1 = *(const float4*)(src + 4);
    float4 f2 = *(const float4*)(src + 8),  f3 = *(const float4*)(src + 12);
    p0.a[0]=f2bf(f0.x); p0.a[1]=f2bf(f0.y); p0.a[2]=f2bf(f0.z); p0.a[3]=f2bf(f0.w);
    p0.a[4]=f2bf(f1.x); p0.a[5]=f2bf(f1.y); p0.a[6]=f2bf(f1.z); p0.a[7]=f2bf(f1.w);
    p1.a[0]=f2bf(f2.x); p1.a[1]=f2bf(f2.y); p1.a[2]=f2bf(f2.z); p1.a[3]=f2bf(f2.w);
    p1.a[4]=f2bf(f3.x); p1.a[5]=f2bf(f3.y); p1.a[6]=f2bf(f3.z); p1.a[7]=f2bf(f3.w);
    *(uint4*)&Ts[lr][lc]     = p0.v;
    *(uint4*)&Ts[lr][lc + 8] = p1.v;
    __syncthreads();
    union { u16 a[8]; uint4 v; } q0, q1;
#pragma unroll
    for (int j = 0; j < 8; ++j) q0.a[j] = Ts[lc + j][lr];
#pragma unroll
    for (int j = 0; j < 8; ++j) q1.a[j] = Ts[lc + 8 + j][lr];
    u16* dst = Wt + (size_t)(n0 + lr) * 1024 + k0 + lc;
    *(uint4*)dst       = q0.v;
    *(uint4*)(dst + 8) = q1.v;
}

// ---------------------------------------------------------------------------
// Fused Q+KV GEMM (1408 blocks of 128x128, BK=32, m97-style).
// ---------------------------------------------------------------------------
__global__ __launch_bounds__(256, 2)
void gemm_qkv(const u16* __restrict__ A, const u16* __restrict__ Wqt,
              const u16* __restrict__ Wkt, u16* __restrict__ q,
              u16* __restrict__ Kh, u16* __restrict__ Vh)
{
    __shared__ __align__(16) u16 smem[17408];   // main: As|Bs; V-epi: T[128][136]
    u16* As = smem;
    u16* Bs = smem + 4096;

    const int t = threadIdx.x, w = t >> 6;
    const int lane = t & 63, quad = lane >> 4, l16 = lane & 15;
    const int id = blockIdx.x;
    const bool qm = id >= 1280;
    int m0, n0; const u16* Bt;
    if (qm) { int t2 = id - 1280; m0 = (t2 >> 3) * 128; n0 = (t2 & 7) * 128; Bt = Wqt; }
    else    { m0 = (id >> 4) * 128; n0 = (id & 15) * 128; Bt = Wkt; }
    const int wr = (w >> 1) * 64, wc = (w & 1) * 64;

    const int sr0 = w * 32 + (lane >> 2), sr1 = sr0 + 16;
    const int cg  = (lane & 3) ^ ((lane >> 4) & 3);
    u16* abase = As + w * 1024;
    u16* bbase = Bs + w * 1024;

    const u16 *ar0, *ar1;
    {
        int g0 = m0 + sr0, g1 = m0 + sr1;
        if (qm) {
            ar0 = A + ((size_t)(g0 >> 10) * 5120 + (g0 & 1023)) * 1024;
            ar1 = A + ((size_t)(g1 >> 10) * 5120 + (g1 & 1023)) * 1024;
        } else {
            ar0 = A + (size_t)g0 * 1024;
            ar1 = A + (size_t)g1 * 1024;
        }
        ar0 += cg * 8; ar1 += cg * 8;
    }
    const u16* br0 = Bt + (size_t)(n0 + sr0) * 1024 + cg * 8;
    const u16* br1 = Bt + (size_t)(n0 + sr1) * 1024 + cg * 8;

    f32x4 acc[4][4] = {};
    const int sel = (quad ^ (l16 >> 2)) * 8;

    for (int k0 = 0; k0 < 1024; k0 += 32) {
        async16(ar0 + k0, abase);
        async16(ar1 + k0, abase + 512);
        async16(br0 + k0, bbase);
        async16(br1 + k0, bbase + 512);
        __syncthreads();

        bf16x8 av[4], bv[4];
#pragma unroll
        for (int i = 0; i < 4; ++i)
            av[i] = *(const bf16x8*)&As[(wr + i * 16 + l16) * 32 + sel];
#pragma unroll
        for (int j = 0; j < 4; ++j)
            bv[j] = *(const bf16x8*)&Bs[(wc + j * 16 + l16) * 32 + sel];
#pragma unroll
        for (int i = 0; i < 4; ++i)
#pragma unroll
            for (int j = 0; j < 4; ++j)
                acc[i][j] = __builtin_amdgcn_mfma_f32_16x16x32_bf16(av[i], bv[j], acc[i][j], 0, 0, 0);
        __syncthreads();
    }

    // Epilogue. C/D layout: col=lane&15, row=quad*4+reg.
    if (qm) {
        const float SC = 0.180336880f;   // 0.125 * log2(e) folded into q
#pragma unroll
        for (int j = 0; j < 4; ++j) {
            int col = n0 + wc + j * 16 + l16;
#pragma unroll
            for (int i = 0; i < 4; ++i) {
                int rowb = m0 + wr + i * 16 + quad * 4;
#pragma unroll
                for (int r = 0; r < 4; ++r)
                    q[(size_t)(rowb + r) * 1024 + col] = f2bf(acc[i][j][r] * SC);
            }
        }
        return;
    }
    int b = m0 >= 5120;
    int keyb = m0 - b * 5120;
    if (n0 < 1024) {
        // K: direct stores (32-B runs per key row)
#pragma unroll
        for (int j = 0; j < 4; ++j) {
            int col = n0 + wc + j * 16 + l16;
#pragma unroll
            for (int i = 0; i < 4; ++i) {
                int rowb = m0 + wr + i * 16 + quad * 4;
                int key = rowb - b * 5120;
                int bh = b * 16 + (col >> 6), d = col & 63;
                u16* dst = Kh + ((size_t)bh * 5120 + key) * 64 + d;
#pragma unroll
                for (int r = 0; r < 4; ++r) dst[r * 64] = f2bf(acc[i][j][r]);
            }
        }
    } else {
        // V: restage through LDS -> fully coalesced Vh[bh][d][key] writes
        u16* T = smem;   // [128][136]
#pragma unroll
        for (int j = 0; j < 4; ++j) {
            int d2 = wc + j * 16 + l16;
#pragma unroll
            for (int i = 0; i < 4; ++i) {
                int kl = wr + i * 16 + quad * 4;
                union { u16 a[4]; uint2 v; } pk;
#pragma unroll
                for (int r = 0; r < 4; ++r) pk.a[r] = f2bf(acc[i][j][r]);
                *(uint2*)&T[d2 * 136 + kl] = pk.v;
            }
        }
        __syncthreads();
        int hb = (n0 - 1024) >> 6;
#pragma unroll
        for (int p = 0; p < 8; ++p) {
            int idx = p * 256 + t;
            int d2 = idx >> 4, k0c = (idx & 15) * 8;
            uint4 vv = *(const uint4*)&T[d2 * 136 + k0c];
            int bh = b * 16 + hb + (d2 >> 6), d = d2 & 63;
            *(uint4*)(Vh + ((size_t)bh * 64 + d) * 5120 + keyb + k0c) = vv;
        }
    }
}

// ---------------------------------------------------------------------------
// Out-proj GEMM: out[2048,1024] fp32 = ao @ Wpt^T + bias. 128x64 tile.
// ---------------------------------------------------------------------------
__global__ __launch_bounds__(256, 2)
void gemm_proj(const u16* __restrict__ A, const u16* __restrict__ Bt,
               const float* __restrict__ bias, float* __restrict__ Cf)
{
    __shared__ __align__(16) u16 As[128 * 32];
    __shared__ __align__(16) u16 Bs[64 * 32];

    const int t = threadIdx.x, w = t >> 6;
    const int lane = t & 63, quad = lane >> 4, l16 = lane & 15;
    const int m0 = blockIdx.y * 128, n0 = blockIdx.x * 64;
    const int wr = w * 32;

    const int sr0 = w * 32 + (lane >> 2), sr1 = sr0 + 16;
    const int cg  = (lane & 3) ^ ((lane >> 4) & 3);
    u16* abase = As + w * 1024;
    u16* bbase = Bs + w * 512;

    const u16* ar0 = A + (size_t)(m0 + sr0) * 1024 + cg * 8;
    const u16* ar1 = A + (size_t)(m0 + sr1) * 1024 + cg * 8;
    const u16* br0 = Bt + (size_t)(n0 + w * 16 + (lane >> 2)) * 1024 + cg * 8;

    f32x4 acc[2][4] = {};
    const int sel = (quad ^ (l16 >> 2)) * 8;

    for (int k0 = 0; k0 < 1024; k0 += 32) {
        async16(ar0 + k0, abase);
        async16(ar1 + k0, abase + 512);
        async16(br0 + k0, bbase);
        __syncthreads();

        bf16x8 av[2], bv[4];
#pragma unroll
        for (int i = 0; i < 2; ++i)
            av[i] = *(const bf16x8*)&As[(wr + i * 16 + l16) * 32 + sel];
#pragma unroll
        for (int j = 0; j < 4; ++j)
            bv[j] = *(const bf16x8*)&Bs[(j * 16 + l16) * 32 + sel];
#pragma unroll
        for (int i = 0; i < 2; ++i)
#pragma unroll
            for (int j = 0; j < 4; ++j)
                acc[i][j] = __builtin_amdgcn_mfma_f32_16x16x32_bf16(av[i], bv[j], acc[i][j], 0, 0, 0);
        __syncthreads();
    }

#pragma unroll
    for (int j = 0; j < 4; ++j) {
        int col = n0 + j * 16 + l16;
        float bvl = bias[col];
#pragma unroll
        for (int i = 0; i < 2; ++i) {
            int rowb = m0 + wr + i * 16 + quad * 4;
#pragma unroll
            for (int r = 0; r < 4; ++r)
                Cf[(size_t)(rowb + r) * 1024 + col] = acc[i][j][r] + bvl;
        }
    }
}

// ---------------------------------------------------------------------------
// Split-K flash attention, max-occupancy variant (R7 post-mortem: latency-
// bound, issue work ~6x below wall clock -> add TLP to the HW wave cap).
//  * chunk = 32 keys, 32 iters; LDS 16 KB (Ks dbuf 8K + Vt 4K + Ps 4K)
//  * wave = 16 q-rows, block = 64 rows; grid = 5 part x 16 qt x 32 bh = 2560
//    = 10 blocks/CU -> 8 resident (32-wave/CU cap).
//  * XCD decode: 16 qt of each (part,bh) pinned to one XCD (R5-proven).
//  * 4-slot layouts: V slot s = keys {4s+i, 4s+16+i}; P packed to the same
//    slot/word order (k-pairing of PV A/B frags matches element-for-element);
//    phys slot = s ^ ((row>>1)&3) -> 2-way-free reads.
// ---------------------------------------------------------------------------
__global__ __launch_bounds__(256, 4)
void attn_k(const u16* __restrict__ Q, const u16* __restrict__ Kh,
            const u16* __restrict__ Vh, u16* __restrict__ Op,
            float* __restrict__ Lp)
{
    __shared__ __align__(16) u16 Ks[2][2048]; // dbuf [key32][slot8^(key&7)][8]
    __shared__ __align__(16) u16 Vt[2048];    // [d64][slot4^((d>>1)&3)][8]
    __shared__ __align__(16) u16 Ps[2048];    // [wave][row16][slot4^((r>>1)&3)][8]

    const int tid  = threadIdx.x;
    const int wave = tid >> 6, lane = tid & 63;
    const int quad = lane >> 4, l16 = lane & 15;
    const int bx = blockIdx.x;
    const int x   = bx & 7;                  // XCD slot (round-robin dispatch)
    const int seq = bx >> 3;                 // 0..319 per-XCD sequence
    const int qt  = seq & 15;
    const int kg  = seq >> 4;                // 0..19
    const int g   = x + 8 * kg;              // group = (part, bh), 0..159
    const int part = g >> 5;                 // 0..4 (1024 keys each)
    const int bh   = g & 31;
    const int h = bh & 15, b = bh >> 4;

    const int qrow0 = b * 1024 + qt * 64 + wave * 16;
    const u16* qbase = Q + (size_t)qrow0 * 1024 + h * 64;

    bf16x8 aq0 = *(const bf16x8*)(qbase + (size_t)l16 * 1024 +      quad * 8);
    bf16x8 aq1 = *(const bf16x8*)(qbase + (size_t)l16 * 1024 + 32 + quad * 8);

    union { u32 u[4]; bf16x8 v; } onesf;
#pragma unroll
    for (int i = 0; i < 4; ++i) onesf.u[i] = 0x3F803F80u;

    f32x4 o[4] = {};
    f32x4 lacc = {};

    const u16* kbase = Kh + (size_t)bh * 5120 * 64;
    const u16* vbase = Vh + (size_t)bh * 64 * 5120;
    const int l7  = l16 & 7;
    const int sw4 = (l16 >> 1) & 3;          // read-side 4-slot swizzle key
    u16* psw = Ps + wave * 512;
    const int m_beg = part * 1024;

    // K async source (inverse-swizzled, 8 slots per 64-u16 key row).
    const int keyA = tid >> 3;               // 0..31
    const int chA  = (tid & 7) ^ (keyA & 7);
    const u16* kga = kbase + (size_t)(m_beg + keyA) * 64 + chA * 8;
    u16* klds = &Ks[0][0] + wave * 512;      // lane*16B implicit

    // V staging: thread -> d = tid>>2, key-group vc = tid&3.
    const int vd = tid >> 2, vc = tid & 3;
    const u16* vptr = vbase + (size_t)vd * 5120 + m_beg + vc * 4;
    u16* vdst = Vt + vd * 32 + ((vc ^ ((vd >> 1) & 3)) << 3);

    // Prologue: chunk 0 loads.
    async16(kga, klds);
    uint2 g0 = *(const uint2*)(vptr);
    uint2 g1 = *(const uint2*)(vptr + 16);

    for (int c = 0; c < 32; ++c) {
        {   // V pack: slot vc = keys {4vc+i, 4vc+16+i}, words i=0..3
            uint4 ov;
            ov.x = __builtin_amdgcn_perm(g1.x, g0.x, 0x05040100u);
            ov.y = __builtin_amdgcn_perm(g1.x, g0.x, 0x07060302u);
            ov.z = __builtin_amdgcn_perm(g1.y, g0.y, 0x05040100u);
            ov.w = __builtin_amdgcn_perm(g1.y, g0.y, 0x07060302u);
            *(uint4*)vdst = ov;
        }
        __syncthreads();   // Vt + Ks[c&1] ready

        // Issue chunk c+1 loads after the barrier; compute phase hides them.
        if (c < 31) {
            async16(kga + (size_t)(c + 1) * 2048,
                    &Ks[0][0] + ((c + 1) & 1) * 2048 + wave * 512);
            const u16* vp = vptr + (c + 1) * 32;
            g0 = *(const uint2*)(vp);
            g1 = *(const uint2*)(vp + 16);
        }

        const u16* KsC = &Ks[0][0] + (c & 1) * 2048;
        f32x4 s0 = {}, s1 = {};
        __builtin_amdgcn_s_setprio(1);
        {   // keys 0..15 (row l16) and 16..31 (row 16+l16)
            const u16* kr0 = KsC + l16 * 64;
            bf16x8 a0 = *(const bf16x8*)(kr0 + ((quad       ^ l7) << 3));
            bf16x8 a1 = *(const bf16x8*)(kr0 + (((4 + quad) ^ l7) << 3));
            s0 = __builtin_amdgcn_mfma_f32_16x16x32_bf16(aq0, a0, s0, 0, 0, 0);
            s0 = __builtin_amdgcn_mfma_f32_16x16x32_bf16(aq1, a1, s0, 0, 0, 0);
            const u16* kr1 = KsC + (16 + l16) * 64;
            bf16x8 b0 = *(const bf16x8*)(kr1 + ((quad       ^ l7) << 3));
            bf16x8 b1 = *(const bf16x8*)(kr1 + (((4 + quad) ^ l7) << 3));
            s1 = __builtin_amdgcn_mfma_f32_16x16x32_bf16(aq0, b0, s1, 0, 0, 0);
            s1 = __builtin_amdgcn_mfma_f32_16x16x32_bf16(aq1, b1, s1, 0, 0, 0);
        }
        __builtin_amdgcn_s_setprio(0);

        // Softmax: lane holds keys (l16, 16+l16) for rows quad*4+r ->
        // word (l16&3) of logical slot (l16>>2), phys slot ^= ((row>>1)&3).
#pragma unroll
        for (int r = 0; r < 4; ++r) {
            float e0 = exp2f(s0[r]);
            float e1 = exp2f(s1[r]);
            u32 pw = __builtin_amdgcn_perm(fbits(e1), fbits(e0), 0x07060302u);
            int qr = quad * 4 + r;
            *(u32*)(psw + qr * 32 + (((l16 >> 2) ^ ((qr >> 1) & 3)) << 3)
                        + ((l16 & 3) << 1)) = pw;
        }

        asm volatile("s_waitcnt lgkmcnt(0)" ::: "memory");

        bf16x8 pf = *(const bf16x8*)(psw + l16 * 32 + ((quad ^ sw4) << 3));

        __builtin_amdgcn_s_setprio(1);
        lacc = __builtin_amdgcn_mfma_f32_16x16x32_bf16(pf, onesf.v, lacc, 0, 0, 0);
#pragma unroll
        for (int dt = 0; dt < 4; ++dt) {
            bf16x8 vf = *(const bf16x8*)(Vt + (dt * 16 + l16) * 32 + ((quad ^ sw4) << 3));
            o[dt] = __builtin_amdgcn_mfma_f32_16x16x32_bf16(pf, vf, o[dt], 0, 0, 0);
        }
        __builtin_amdgcn_s_setprio(0);
        __syncthreads();   // PV done; next iter may overwrite Vt/Ps
    }

    const int Rb = bh * 1024 + qt * 64 + wave * 16;
    u16* obase = Op + ((size_t)part << 21);
#pragma unroll
    for (int dt = 0; dt < 4; ++dt)
#pragma unroll
        for (int r = 0; r < 4; ++r) {
            int R = Rb + quad * 4 + r;
            obase[(size_t)R * 64 + dt * 16 + l16] = f2bf(o[dt][r]);
        }
    if (l16 == 0) {
#pragma unroll
        for (int r = 0; r < 4; ++r)
            Lp[part * 32768 + Rb + quad * 4 + r] = lacc[r];
    }
}

// ---------------------------------------------------------------------------
// Combine: ao[b,n,h*64+d] = (sum_p Op[p]) / (sum_p Lp[p]).  5 parts.
// ---------------------------------------------------------------------------
__global__ void comb_k(const u16* __restrict__ Op, const float* __restrict__ Lp,
                       u16* __restrict__ ao)
{
    int t = blockIdx.x * 256 + threadIdx.x;
    int R = t >> 4, dg = (t & 15) * 4;
    float l = Lp[R] + Lp[32768 + R] + Lp[65536 + R] + Lp[98304 + R] + Lp[131072 + R];
    float a[4] = {0.f, 0.f, 0.f, 0.f};
#pragma unroll
    for (int p = 0; p < 5; ++p) {
        union { u16 a[4]; uint2 v; } w;
        w.v = *(const uint2*)(Op + ((size_t)p << 21) + (size_t)R * 64 + dg);
#pragma unroll
        for (int j = 0; j < 4; ++j) a[j] += bf2f(w.a[j]);
    }
    float inv = 1.f / l;
    int bh = R >> 10, n = R & 1023, b = bh >> 4, h = bh & 15;
    union { u16 a[4]; uint2 v; } out;
#pragma unroll
    for (int j = 0; j < 4; ++j) out.a[j] = f2bf(a[j] * inv);
    *(uint2*)(ao + (size_t)(b * 1024 + n) * 1024 + h * 64 + dg) = out.v;
}

// ---------------------------------------------------------------------------
// Workspace map unchanged (5 parts): Op [4,24M), Lp in dead Wkt half [24M+).
// ---------------------------------------------------------------------------
extern "C" void kernel_launch(void* const* d_in, const int* in_sizes, int n_in,
                              void* d_out, int out_size, void* d_ws, size_t ws_size,
                              hipStream_t stream)
{
    const float* x_obj = (const float*)d_in[0];
    const float* x_ctx = (const float*)d_in[1];
    const float* Wq    = (const float*)d_in[2];
    const float* Wkv   = (const float*)d_in[3];
    const float* Wproj = (const float*)d_in[4];
    const float* bproj = (const float*)d_in[5];
    float* out = (float*)d_out;                   // [2,1024,1024] fp32

    u16* Xc  = (u16*)d_ws;                        // [10240][1024]   20 MB
    u16* ao  = Xc;                                // alias (attn out, 4 MB)
    u16* Op  = Xc + (size_t)2097152;              // alias (partials, 20 MB)
    u16* Wqt = Xc  + (size_t)10485760;            // 2 MB
    u16* Wkt = Wqt + (size_t)1048576;             // 4 MB
    u16* Wpt = Wkt + (size_t)2097152;             // 2 MB
    u16* q   = Wpt + (size_t)1048576;             // 4 MB
    u16* Kh  = q   + (size_t)2097152;             // [32][5120][64] 20 MB
    u16* Vh  = Kh  + (size_t)10485760;            // [32][64][5120] 20 MB
    float* Lp = (float*)(Wkt + (size_t)1048576);  // [5][32768] in dead Wkt half

    dim3 blk(256);
    cvt_all_k<<<dim3(11264), blk, 0, stream>>>(x_obj, x_ctx, Xc,
                                               Wq, Wkv, Wproj, Wqt, Wkt, Wpt);
    gemm_qkv<<<dim3(1408), blk, 0, stream>>>(Xc, Wqt, Wkt, q, Kh, Vh);
    attn_k<<<dim3(2560), blk, 0, stream>>>(q, Kh, Vh, Op, Lp);
    comb_k<<<dim3(2048), blk, 0, stream>>>(Op, Lp, ao);
    gemm_proj<<<dim3(16, 16), blk, 0, stream>>>(ao, Wpt, bproj, out);
}

// Round 9
// 247.524 us; speedup vs baseline: 1.0461x; 1.0461x over previous
//
#include <hip/hip_runtime.h>
#include <stdint.h>

typedef unsigned short u16;
typedef unsigned int   u32;
typedef __attribute__((ext_vector_type(8))) short bf16x8;
typedef __attribute__((ext_vector_type(4))) float f32x4;

__device__ __forceinline__ u16 f2bf(float f) {
    union { float f; u32 u; } v; v.f = f;
    return (u16)((v.u + 0x7FFFu + ((v.u >> 16) & 1u)) >> 16);  // RNE
}
__device__ __forceinline__ float bf2f(u16 h) {
    union { u32 u; float f; } v; v.u = ((u32)h) << 16; return v.f;
}
__device__ __forceinline__ u32 fbits(float f) {
    union { float f; u32 u; } v; v.f = f; return v.u;
}

__device__ __forceinline__ void async16(const u16* g, u16* l) {
    typedef __attribute__((address_space(1))) const u32 gq;
    typedef __attribute__((address_space(3))) u32 lq;
    __builtin_amdgcn_global_load_lds((gq*)g, (lq*)l, 16, 0, 0);
}

// ---------------------------------------------------------------------------
// Prep (fused): blocks 0..10239 concat+convert x rows; 10240.. weight tiles.
// ---------------------------------------------------------------------------
__global__ void cvt_all_k(const float* __restrict__ xo, const float* __restrict__ xc,
                          u16* __restrict__ Xc,
                          const float* __restrict__ Wq, const float* __restrict__ Wkv,
                          const float* __restrict__ Wp,
                          u16* __restrict__ Wqt, u16* __restrict__ Wkt,
                          u16* __restrict__ Wpt)
{
    __shared__ __align__(16) u16 Ts[64][72];
    int id = blockIdx.x, t = threadIdx.x;
    if (id < 10240) {
        int row = id, cid = t * 4;
        int b = row >= 5120, s = row - b * 5120;
        const float* src = (s < 1024)
            ? xo + ((size_t)(b * 1024 + s)) * 1024 + cid
            : xc + ((size_t)(b * 4096 + s - 1024)) * 1024 + cid;
        float4 f = *(const float4*)src;
        union { u16 a[4]; uint2 v; } p;
        p.a[0]=f2bf(f.x); p.a[1]=f2bf(f.y); p.a[2]=f2bf(f.z); p.a[3]=f2bf(f.w);
        *(uint2*)(Xc + (size_t)row * 1024 + cid) = p.v;
        return;
    }
    int wid = id - 10240;
    const float* W; u16* Wt; int N, tile;
    if (wid < 256)      { W = Wq;  Wt = Wqt; N = 1024; tile = wid; }
    else if (wid < 768) { W = Wkv; Wt = Wkt; N = 2048; tile = wid - 256; }
    else                { W = Wp;  Wt = Wpt; N = 1024; tile = wid - 768; }
    int nt = N >> 6;
    int n0 = (tile % nt) * 64, k0 = (tile / nt) * 64;
    int lr = t >> 2, lc = (t & 3) * 16;
    const float* src = W + (size_t)(k0 + lr) * N + n0 + lc;
    union { u16 a[8]; uint4 v; } p0, p1;
    float4 f0 = *(const float4*)(src),      f1 = *(const float4*)(src + 4);
    float4 f2 = *(const float4*)(src + 8),  f3 = *(const float4*)(src + 12);
    p0.a[0]=f2bf(f0.x); p0.a[1]=f2bf(f0.y); p0.a[2]=f2bf(f0.z); p0.a[3]=f2bf(f0.w);
    p0.a[4]=f2bf(f1.x); p0.a[5]=f2bf(f1.y); p0.a[6]=f2bf(f1.z); p0.a[7]=f2bf(f1.w);
    p1.a[0]=f2bf(f2.x); p1.a[1]=f2bf(f2.y); p1.a[2]=f2bf(f2.z); p1.a[3]=f2bf(f2.w);
    p1.a[4]=f2bf(f3.x); p1.a[5]=f2bf(f3.y); p1.a[6]=f2bf(f3.z); p1.a[7]=f2bf(f3.w);
    *(uint4*)&Ts[lr][lc]     = p0.v;
    *(uint4*)&Ts[lr][lc + 8] = p1.v;
    __syncthreads();
    union { u16 a[8]; uint4 v; } q0, q1;
#pragma unroll
    for (int j = 0; j < 8; ++j) q0.a[j] = Ts[lc + j][lr];
#pragma unroll
    for (int j = 0; j < 8; ++j) q1.a[j] = Ts[lc + 8 + j][lr];
    u16* dst = Wt + (size_t)(n0 + lr) * 1024 + k0 + lc;
    *(uint4*)dst       = q0.v;
    *(uint4*)(dst + 8) = q1.v;
}

// ---------------------------------------------------------------------------
// Fused Q+KV GEMM (1408 blocks of 128x128, BK=32, m97-style).
// ---------------------------------------------------------------------------
__global__ __launch_bounds__(256, 2)
void gemm_qkv(const u16* __restrict__ A, const u16* __restrict__ Wqt,
              const u16* __restrict__ Wkt, u16* __restrict__ q,
              u16* __restrict__ Kh, u16* __restrict__ Vh)
{
    __shared__ __align__(16) u16 smem[17408];   // main: As|Bs; V-epi: T[128][136]
    u16* As = smem;
    u16* Bs = smem + 4096;

    const int t = threadIdx.x, w = t >> 6;
    const int lane = t & 63, quad = lane >> 4, l16 = lane & 15;
    const int id = blockIdx.x;
    const bool qm = id >= 1280;
    int m0, n0; const u16* Bt;
    if (qm) { int t2 = id - 1280; m0 = (t2 >> 3) * 128; n0 = (t2 & 7) * 128; Bt = Wqt; }
    else    { m0 = (id >> 4) * 128; n0 = (id & 15) * 128; Bt = Wkt; }
    const int wr = (w >> 1) * 64, wc = (w & 1) * 64;

    const int sr0 = w * 32 + (lane >> 2), sr1 = sr0 + 16;
    const int cg  = (lane & 3) ^ ((lane >> 4) & 3);
    u16* abase = As + w * 1024;
    u16* bbase = Bs + w * 1024;

    const u16 *ar0, *ar1;
    {
        int g0 = m0 + sr0, g1 = m0 + sr1;
        if (qm) {
            ar0 = A + ((size_t)(g0 >> 10) * 5120 + (g0 & 1023)) * 1024;
            ar1 = A + ((size_t)(g1 >> 10) * 5120 + (g1 & 1023)) * 1024;
        } else {
            ar0 = A + (size_t)g0 * 1024;
            ar1 = A + (size_t)g1 * 1024;
        }
        ar0 += cg * 8; ar1 += cg * 8;
    }
    const u16* br0 = Bt + (size_t)(n0 + sr0) * 1024 + cg * 8;
    const u16* br1 = Bt + (size_t)(n0 + sr1) * 1024 + cg * 8;

    f32x4 acc[4][4] = {};
    const int sel = (quad ^ (l16 >> 2)) * 8;

    for (int k0 = 0; k0 < 1024; k0 += 32) {
        async16(ar0 + k0, abase);
        async16(ar1 + k0, abase + 512);
        async16(br0 + k0, bbase);
        async16(br1 + k0, bbase + 512);
        __syncthreads();

        bf16x8 av[4], bv[4];
#pragma unroll
        for (int i = 0; i < 4; ++i)
            av[i] = *(const bf16x8*)&As[(wr + i * 16 + l16) * 32 + sel];
#pragma unroll
        for (int j = 0; j < 4; ++j)
            bv[j] = *(const bf16x8*)&Bs[(wc + j * 16 + l16) * 32 + sel];
#pragma unroll
        for (int i = 0; i < 4; ++i)
#pragma unroll
            for (int j = 0; j < 4; ++j)
                acc[i][j] = __builtin_amdgcn_mfma_f32_16x16x32_bf16(av[i], bv[j], acc[i][j], 0, 0, 0);
        __syncthreads();
    }

    // Epilogue. C/D layout: col=lane&15, row=quad*4+reg.
    if (qm) {
        const float SC = 0.180336880f;   // 0.125 * log2(e) folded into q
#pragma unroll
        for (int j = 0; j < 4; ++j) {
            int col = n0 + wc + j * 16 + l16;
#pragma unroll
            for (int i = 0; i < 4; ++i) {
                int rowb = m0 + wr + i * 16 + quad * 4;
#pragma unroll
                for (int r = 0; r < 4; ++r)
                    q[(size_t)(rowb + r) * 1024 + col] = f2bf(acc[i][j][r] * SC);
            }
        }
        return;
    }
    int b = m0 >= 5120;
    int keyb = m0 - b * 5120;
    if (n0 < 1024) {
        // K: direct stores (32-B runs per key row)
#pragma unroll
        for (int j = 0; j < 4; ++j) {
            int col = n0 + wc + j * 16 + l16;
#pragma unroll
            for (int i = 0; i < 4; ++i) {
                int rowb = m0 + wr + i * 16 + quad * 4;
                int key = rowb - b * 5120;
                int bh = b * 16 + (col >> 6), d = col & 63;
                u16* dst = Kh + ((size_t)bh * 5120 + key) * 64 + d;
#pragma unroll
                for (int r = 0; r < 4; ++r) dst[r * 64] = f2bf(acc[i][j][r]);
            }
        }
    } else {
        // V: restage through LDS -> fully coalesced Vh[bh][d][key] writes
        u16* T = smem;   // [128][136]
#pragma unroll
        for (int j = 0; j < 4; ++j) {
            int d2 = wc + j * 16 + l16;
#pragma unroll
            for (int i = 0; i < 4; ++i) {
                int kl = wr + i * 16 + quad * 4;
                union { u16 a[4]; uint2 v; } pk;
#pragma unroll
                for (int r = 0; r < 4; ++r) pk.a[r] = f2bf(acc[i][j][r]);
                *(uint2*)&T[d2 * 136 + kl] = pk.v;
            }
        }
        __syncthreads();
        int hb = (n0 - 1024) >> 6;
#pragma unroll
        for (int p = 0; p < 8; ++p) {
            int idx = p * 256 + t;
            int d2 = idx >> 4, k0c = (idx & 15) * 8;
            uint4 vv = *(const uint4*)&T[d2 * 136 + k0c];
            int bh = b * 16 + hb + (d2 >> 6), d = d2 & 63;
            *(uint4*)(Vh + ((size_t)bh * 64 + d) * 5120 + keyb + k0c) = vv;
        }
    }
}

// ---------------------------------------------------------------------------
// Out-proj GEMM: out[2048,1024] fp32 = ao @ Wpt^T + bias. 128x64 tile.
// ---------------------------------------------------------------------------
__global__ __launch_bounds__(256, 2)
void gemm_proj(const u16* __restrict__ A, const u16* __restrict__ Bt,
               const float* __restrict__ bias, float* __restrict__ Cf)
{
    __shared__ __align__(16) u16 As[128 * 32];
    __shared__ __align__(16) u16 Bs[64 * 32];

    const int t = threadIdx.x, w = t >> 6;
    const int lane = t & 63, quad = lane >> 4, l16 = lane & 15;
    const int m0 = blockIdx.y * 128, n0 = blockIdx.x * 64;
    const int wr = w * 32;

    const int sr0 = w * 32 + (lane >> 2), sr1 = sr0 + 16;
    const int cg  = (lane & 3) ^ ((lane >> 4) & 3);
    u16* abase = As + w * 1024;
    u16* bbase = Bs + w * 512;

    const u16* ar0 = A + (size_t)(m0 + sr0) * 1024 + cg * 8;
    const u16* ar1 = A + (size_t)(m0 + sr1) * 1024 + cg * 8;
    const u16* br0 = Bt + (size_t)(n0 + w * 16 + (lane >> 2)) * 1024 + cg * 8;

    f32x4 acc[2][4] = {};
    const int sel = (quad ^ (l16 >> 2)) * 8;

    for (int k0 = 0; k0 < 1024; k0 += 32) {
        async16(ar0 + k0, abase);
        async16(ar1 + k0, abase + 512);
        async16(br0 + k0, bbase);
        __syncthreads();

        bf16x8 av[2], bv[4];
#pragma unroll
        for (int i = 0; i < 2; ++i)
            av[i] = *(const bf16x8*)&As[(wr + i * 16 + l16) * 32 + sel];
#pragma unroll
        for (int j = 0; j < 4; ++j)
            bv[j] = *(const bf16x8*)&Bs[(j * 16 + l16) * 32 + sel];
#pragma unroll
        for (int i = 0; i < 2; ++i)
#pragma unroll
            for (int j = 0; j < 4; ++j)
                acc[i][j] = __builtin_amdgcn_mfma_f32_16x16x32_bf16(av[i], bv[j], acc[i][j], 0, 0, 0);
        __syncthreads();
    }

#pragma unroll
    for (int j = 0; j < 4; ++j) {
        int col = n0 + j * 16 + l16;
        float bvl = bias[col];
#pragma unroll
        for (int i = 0; i < 2; ++i) {
            int rowb = m0 + wr + i * 16 + quad * 4;
#pragma unroll
            for (int r = 0; r < 4; ++r)
                Cf[(size_t)(rowb + r) * 1024 + col] = acc[i][j][r] + bvl;
        }
    }
}

// ---------------------------------------------------------------------------
// Split-K flash attention (R8 post-mortem: TLP doesn't help; R8's 4-slot
// layouts bank-conflict. Revert to R7's proven 64-key/128-B-row/8-slot
// geometry, shorten the serial chain):
//  * K rows interleaved in LDS: row r holds key k(r)=2*(r&31)+(r>>5). QK then
//    leaves each lane holding CONSECUTIVE key pairs (2*l16,2*l16+1,+32,+33),
//    so P packs in natural key order and V needs NO transpose.
//  * V staged by global_load_lds straight from Vh[d][key] (pre-swizzled
//    source, linear dest) -- kills 4 reg loads + 8 perms + 2 ds_writes and
//    the V vmcnt stall per thread-iter.
//  * Ks AND Vt double-buffered (40 KB total) -> end-of-iteration barrier
//    removed: ONE barrier per chunk (next chunk's asyncs target the other
//    buffer; Ps is per-wave, per-wave DS ordering protects rt reuse).
//  * P-write banks: each u32 store spreads 2-way over all 32 banks (X=qr&7,
//    slot pair {s, s^4} alternates by quad parity) -- free; all reads keep
//    R7's measured-0-conflict pattern.
// ---------------------------------------------------------------------------
__global__ __launch_bounds__(256, 4)
void attn_k(const u16* __restrict__ Q, const u16* __restrict__ Kh,
            const u16* __restrict__ Vh, u16* __restrict__ Op,
            float* __restrict__ Lp)
{
    __shared__ __align__(16) u16 Ks[2][4096]; // [buf][row64][slot8^(row&7)][8]
    __shared__ __align__(16) u16 Vt[2][4096]; // [buf][d64][slot8^(d&7)][8]
    __shared__ __align__(16) u16 Ps[4096];    // [wave][row16][slot8^(row&7)][8]

    const int tid  = threadIdx.x;
    const int wave = tid >> 6, lane = tid & 63;
    const int quad = lane >> 4, l16 = lane & 15;
    const int bx = blockIdx.x;
    const int x   = bx & 7;                  // XCD slot (round-robin dispatch)
    const int seq = bx >> 3;                 // 0..159 per-XCD sequence
    const int qt  = seq & 7;
    const int kg  = seq >> 3;                // 0..19
    const int g   = x + 8 * kg;              // group = (part, bh), 0..159
    const int part = g >> 5;                 // 0..4 (1024 keys each)
    const int bh   = g & 31;
    const int h = bh & 15, b = bh >> 4;

    const int qrow0 = b * 1024 + qt * 128 + wave * 32;
    const u16* qbase = Q + (size_t)qrow0 * 1024 + h * 64;

    bf16x8 aq[2][2];
#pragma unroll
    for (int rt = 0; rt < 2; ++rt) {
        aq[rt][0] = *(const bf16x8*)(qbase + (size_t)(rt * 16 + l16) * 1024 +      quad * 8);
        aq[rt][1] = *(const bf16x8*)(qbase + (size_t)(rt * 16 + l16) * 1024 + 32 + quad * 8);
    }

    union { u32 u[4]; bf16x8 v; } onesf;
#pragma unroll
    for (int i = 0; i < 4; ++i) onesf.u[i] = 0x3F803F80u;

    f32x4 o[2][4] = {};
    f32x4 lacc[2] = {};

    const u16* kbase = Kh + (size_t)bh * 5120 * 64;
    const u16* vbase = Vh + (size_t)bh * 64 * 5120;
    const int l7 = l16 & 7;
    u16* psw = Ps + wave * 1024;
    const int m_beg = part * 1024;

    // Async staging geometry (per thread): LDS row r1 = tid>>3 (first half)
    // and 32+r1 (second half); phys slot sl = tid&7; logical slot sl^(r1&7).
    const int r1 = tid >> 3;
    const int sl = tid & 7;
    const int xs = sl ^ (r1 & 7);
    // K: LDS row r holds key kappa(r); kappa(r1) = 2*r1, kappa(32+r1) = 2*r1+1.
    const u16* kga = kbase + (size_t)(m_beg + 2 * r1) * 64 + xs * 8;
    // V: natural key order; row d = r1 / 32+r1, keys = logical_slot*8 ...
    const u16* vga = vbase + (size_t)r1 * 5120 + m_beg + xs * 8;
    u16* kldsw = &Ks[0][0] + wave * 512;     // + lane*16B implicit
    u16* vldsw = &Vt[0][0] + wave * 512;

    // Prologue: chunk 0 into buffer 0 (latency exposed once).
    async16(kga,              kldsw);
    async16(kga + 64,         kldsw + 2048);          // key +1 (row 32+r1)
    async16(vga,              vldsw);
    async16(vga + 32 * 5120,  vldsw + 2048);          // d +32

    for (int c = 0; c < 16; ++c) {
        __syncthreads();   // drain own asyncs for chunk c; all buffers ready

        // Issue chunk c+1 into the other buffer; full compute phase hides it.
        if (c < 15) {
            const int nb = (c + 1) & 1;
            const u16* ka = kga + (size_t)(c + 1) * 4096;   // +64 keys
            const u16* va = vga + (c + 1) * 64;             // +64 keys
            u16* kd = &Ks[nb][0] + wave * 512;
            u16* vd = &Vt[nb][0] + wave * 512;
            async16(ka,             kd);
            async16(ka + 64,        kd + 2048);
            async16(va,             vd);
            async16(va + 32 * 5120, vd + 2048);
        }

        const u16* KsC = &Ks[c & 1][0];
        const u16* VtC = &Vt[c & 1][0];

        f32x4 s[2][4] = {};
        __builtin_amdgcn_s_setprio(1);
#pragma unroll
        for (int nt = 0; nt < 4; ++nt) {
            const u16* krow = KsC + (nt * 16 + l16) * 64;
            bf16x8 kb0 = *(const bf16x8*)(krow + ((quad     ^ l7) * 8));
            bf16x8 kb1 = *(const bf16x8*)(krow + (((4+quad) ^ l7) * 8));
#pragma unroll
            for (int rt = 0; rt < 2; ++rt) {
                s[rt][nt] = __builtin_amdgcn_mfma_f32_16x16x32_bf16(aq[rt][0], kb0, s[rt][nt], 0, 0, 0);
                s[rt][nt] = __builtin_amdgcn_mfma_f32_16x16x32_bf16(aq[rt][1], kb1, s[rt][nt], 0, 0, 0);
            }
        }
        __builtin_amdgcn_s_setprio(0);

        // Per-rt: softmax -> P (natural key order) -> l,PV.
        // Lane holds keys: s[rt][0]=2*l16, s[rt][2]=2*l16+1 (pair @ word l16&3,
        // slot l16>>2), s[rt][1]=32+2*l16, s[rt][3]=33+2*l16 (slot 4+(l16>>2)).
#pragma unroll
        for (int rt = 0; rt < 2; ++rt) {
#pragma unroll
            for (int r = 0; r < 4; ++r) {
                float e0 = exp2f(s[rt][0][r]);
                float e1 = exp2f(s[rt][1][r]);
                float e2 = exp2f(s[rt][2][r]);
                float e3 = exp2f(s[rt][3][r]);
                u32 pwx = __builtin_amdgcn_perm(fbits(e2), fbits(e0), 0x07060302u);
                u32 pwy = __builtin_amdgcn_perm(fbits(e3), fbits(e1), 0x07060302u);
                int qr = quad * 4 + r;
                u16* prow = psw + qr * 64;
                *(u32*)(prow + ((( (l16 >> 2)    ) ^ (qr & 7)) * 8) + (l16 & 3) * 2) = pwx;
                *(u32*)(prow + ((( (l16 >> 2) + 4) ^ (qr & 7)) * 8) + (l16 & 3) * 2) = pwy;
            }

            asm volatile("s_waitcnt lgkmcnt(0)" ::: "memory");

            const u16* prow = psw + l16 * 64;
            bf16x8 pf0 = *(const bf16x8*)(prow + ((quad     ^ l7) * 8));
            bf16x8 pf1 = *(const bf16x8*)(prow + (((4+quad) ^ l7) * 8));

            __builtin_amdgcn_s_setprio(1);
            lacc[rt] = __builtin_amdgcn_mfma_f32_16x16x32_bf16(pf0, onesf.v, lacc[rt], 0, 0, 0);
            lacc[rt] = __builtin_amdgcn_mfma_f32_16x16x32_bf16(pf1, onesf.v, lacc[rt], 0, 0, 0);
#pragma unroll
            for (int dt = 0; dt < 4; ++dt) {
                const u16* vrow = VtC + (dt * 16 + l16) * 64;
                bf16x8 v0 = *(const bf16x8*)(vrow + ((quad     ^ l7) * 8));
                bf16x8 v1 = *(const bf16x8*)(vrow + (((4+quad) ^ l7) * 8));
                o[rt][dt] = __builtin_amdgcn_mfma_f32_16x16x32_bf16(pf0, v0, o[rt][dt], 0, 0, 0);
                o[rt][dt] = __builtin_amdgcn_mfma_f32_16x16x32_bf16(pf1, v1, o[rt][dt], 0, 0, 0);
            }
            __builtin_amdgcn_s_setprio(0);
        }
        // no end barrier: next chunk writes the other Ks/Vt buffer; Ps is
        // per-wave and per-wave DS ops are in-order.
    }

    const int Rb = bh * 1024 + qt * 128 + wave * 32;
    u16* obase = Op + ((size_t)part << 21);
#pragma unroll
    for (int rt = 0; rt < 2; ++rt)
#pragma unroll
        for (int dt = 0; dt < 4; ++dt)
#pragma unroll
            for (int r = 0; r < 4; ++r) {
                int R = Rb + rt * 16 + quad * 4 + r;
                obase[(size_t)R * 64 + dt * 16 + l16] = f2bf(o[rt][dt][r]);
            }
    if (l16 == 0) {
#pragma unroll
        for (int rt = 0; rt < 2; ++rt)
#pragma unroll
            for (int r = 0; r < 4; ++r)
                Lp[part * 32768 + Rb + rt * 16 + quad * 4 + r] = lacc[rt][r];
    }
}

// ---------------------------------------------------------------------------
// Combine: ao[b,n,h*64+d] = (sum_p Op[p]) / (sum_p Lp[p]).  5 parts.
// ---------------------------------------------------------------------------
__global__ void comb_k(const u16* __restrict__ Op, const float* __restrict__ Lp,
                       u16* __restrict__ ao)
{
    int t = blockIdx.x * 256 + threadIdx.x;
    int R = t >> 4, dg = (t & 15) * 4;
    float l = Lp[R] + Lp[32768 + R] + Lp[65536 + R] + Lp[98304 + R] + Lp[131072 + R];
    float a[4] = {0.f, 0.f, 0.f, 0.f};
#pragma unroll
    for (int p = 0; p < 5; ++p) {
        union { u16 a[4]; uint2 v; } w;
        w.v = *(const uint2*)(Op + ((size_t)p << 21) + (size_t)R * 64 + dg);
#pragma unroll
        for (int j = 0; j < 4; ++j) a[j] += bf2f(w.a[j]);
    }
    float inv = 1.f / l;
    int bh = R >> 10, n = R & 1023, b = bh >> 4, h = bh & 15;
    union { u16 a[4]; uint2 v; } out;
#pragma unroll
    for (int j = 0; j < 4; ++j) out.a[j] = f2bf(a[j] * inv);
    *(uint2*)(ao + (size_t)(b * 1024 + n) * 1024 + h * 64 + dg) = out.v;
}

// ---------------------------------------------------------------------------
// Workspace map unchanged (5 parts): Op [4,24M), Lp in dead Wkt half [24M+).
// ---------------------------------------------------------------------------
extern "C" void kernel_launch(void* const* d_in, const int* in_sizes, int n_in,
                              void* d_out, int out_size, void* d_ws, size_t ws_size,
                              hipStream_t stream)
{
    const float* x_obj = (const float*)d_in[0];
    const float* x_ctx = (const float*)d_in[1];
    const float* Wq    = (const float*)d_in[2];
    const float* Wkv   = (const float*)d_in[3];
    const float* Wproj = (const float*)d_in[4];
    const float* bproj = (const float*)d_in[5];
    float* out = (float*)d_out;                   // [2,1024,1024] fp32

    u16* Xc  = (u16*)d_ws;                        // [10240][1024]   20 MB
    u16* ao  = Xc;                                // alias (attn out, 4 MB)
    u16* Op  = Xc + (size_t)2097152;              // alias (partials, 20 MB)
    u16* Wqt = Xc  + (size_t)10485760;            // 2 MB
    u16* Wkt = Wqt + (size_t)1048576;             // 4 MB
    u16* Wpt = Wkt + (size_t)2097152;             // 2 MB
    u16* q   = Wpt + (size_t)1048576;             // 4 MB
    u16* Kh  = q   + (size_t)2097152;             // [32][5120][64] 20 MB
    u16* Vh  = Kh  + (size_t)10485760;            // [32][64][5120] 20 MB
    float* Lp = (float*)(Wkt + (size_t)1048576);  // [5][32768] in dead Wkt half

    dim3 blk(256);
    cvt_all_k<<<dim3(11264), blk, 0, stream>>>(x_obj, x_ctx, Xc,
                                               Wq, Wkv, Wproj, Wqt, Wkt, Wpt);
    gemm_qkv<<<dim3(1408), blk, 0, stream>>>(Xc, Wqt, Wkt, q, Kh, Vh);
    attn_k<<<dim3(1280), blk, 0, stream>>>(q, Kh, Vh, Op, Lp);
    comb_k<<<dim3(2048), blk, 0, stream>>>(Op, Lp, ao);
    gemm_proj<<<dim3(16, 16), blk, 0, stream>>>(ao, Wpt, bproj, out);
}

// Round 10
// 244.375 us; speedup vs baseline: 1.0596x; 1.0129x over previous
//
#include <hip/hip_runtime.h>
#include <stdint.h>

typedef unsigned short u16;
typedef unsigned int   u32;
typedef __attribute__((ext_vector_type(8))) short bf16x8;
typedef __attribute__((ext_vector_type(4))) float f32x4;

__device__ __forceinline__ u16 f2bf(float f) {
    union { float f; u32 u; } v; v.f = f;
    return (u16)((v.u + 0x7FFFu + ((v.u >> 16) & 1u)) >> 16);  // RNE
}
__device__ __forceinline__ float bf2f(u16 h) {
    union { u32 u; float f; } v; v.u = ((u32)h) << 16; return v.f;
}
__device__ __forceinline__ u32 fbits(float f) {
    union { float f; u32 u; } v; v.f = f; return v.u;
}

__device__ __forceinline__ void async16(const u16* g, u16* l) {
    typedef __attribute__((address_space(1))) const u32 gq;
    typedef __attribute__((address_space(3))) u32 lq;
    __builtin_amdgcn_global_load_lds((gq*)g, (lq*)l, 16, 0, 0);
}

// ---------------------------------------------------------------------------
// Prep (fused): blocks 0..10239 concat+convert x rows; 10240.. weight tiles.
// ---------------------------------------------------------------------------
__global__ void cvt_all_k(const float* __restrict__ xo, const float* __restrict__ xc,
                          u16* __restrict__ Xc,
                          const float* __restrict__ Wq, const float* __restrict__ Wkv,
                          const float* __restrict__ Wp,
                          u16* __restrict__ Wqt, u16* __restrict__ Wkt,
                          u16* __restrict__ Wpt)
{
    __shared__ __align__(16) u16 Ts[64][72];
    int id = blockIdx.x, t = threadIdx.x;
    if (id < 10240) {
        int row = id, cid = t * 4;
        int b = row >= 5120, s = row - b * 5120;
        const float* src = (s < 1024)
            ? xo + ((size_t)(b * 1024 + s)) * 1024 + cid
            : xc + ((size_t)(b * 4096 + s - 1024)) * 1024 + cid;
        float4 f = *(const float4*)src;
        union { u16 a[4]; uint2 v; } p;
        p.a[0]=f2bf(f.x); p.a[1]=f2bf(f.y); p.a[2]=f2bf(f.z); p.a[3]=f2bf(f.w);
        *(uint2*)(Xc + (size_t)row * 1024 + cid) = p.v;
        return;
    }
    int wid = id - 10240;
    const float* W; u16* Wt; int N, tile;
    if (wid < 256)      { W = Wq;  Wt = Wqt; N = 1024; tile = wid; }
    else if (wid < 768) { W = Wkv; Wt = Wkt; N = 2048; tile = wid - 256; }
    else                { W = Wp;  Wt = Wpt; N = 1024; tile = wid - 768; }
    int nt = N >> 6;
    int n0 = (tile % nt) * 64, k0 = (tile / nt) * 64;
    int lr = t >> 2, lc = (t & 3) * 16;
    const float* src = W + (size_t)(k0 + lr) * N + n0 + lc;
    union { u16 a[8]; uint4 v; } p0, p1;
    float4 f0 = *(const float4*)(src),      f1 = *(const float4*)(src + 4);
    float4 f2 = *(const float4*)(src + 8),  f3 = *(const float4*)(src + 12);
    p0.a[0]=f2bf(f0.x); p0.a[1]=f2bf(f0.y); p0.a[2]=f2bf(f0.z); p0.a[3]=f2bf(f0.w);
    p0.a[4]=f2bf(f1.x); p0.a[5]=f2bf(f1.y); p0.a[6]=f2bf(f1.z); p0.a[7]=f2bf(f1.w);
    p1.a[0]=f2bf(f2.x); p1.a[1]=f2bf(f2.y); p1.a[2]=f2bf(f2.z); p1.a[3]=f2bf(f2.w);
    p1.a[4]=f2bf(f3.x); p1.a[5]=f2bf(f3.y); p1.a[6]=f2bf(f3.z); p1.a[7]=f2bf(f3.w);
    *(uint4*)&Ts[lr][lc]     = p0.v;
    *(uint4*)&Ts[lr][lc + 8] = p1.v;
    __syncthreads();
    union { u16 a[8]; uint4 v; } q0, q1;
#pragma unroll
    for (int j = 0; j < 8; ++j) q0.a[j] = Ts[lc + j][lr];
#pragma unroll
    for (int j = 0; j < 8; ++j) q1.a[j] = Ts[lc + 8 + j][lr];
    u16* dst = Wt + (size_t)(n0 + lr) * 1024 + k0 + lc;
    *(uint4*)dst       = q0.v;
    *(uint4*)(dst + 8) = q1.v;
}

// ---------------------------------------------------------------------------
// Fused Q+KV GEMM (1408 blocks of 128x128, BK=32, m97-style).
// ---------------------------------------------------------------------------
__global__ __launch_bounds__(256, 2)
void gemm_qkv(const u16* __restrict__ A, const u16* __restrict__ Wqt,
              const u16* __restrict__ Wkt, u16* __restrict__ q,
              u16* __restrict__ Kh, u16* __restrict__ Vh)
{
    __shared__ __align__(16) u16 smem[17408];   // main: As|Bs; V-epi: T[128][136]
    u16* As = smem;
    u16* Bs = smem + 4096;

    const int t = threadIdx.x, w = t >> 6;
    const int lane = t & 63, quad = lane >> 4, l16 = lane & 15;
    const int id = blockIdx.x;
    const bool qm = id >= 1280;
    int m0, n0; const u16* Bt;
    if (qm) { int t2 = id - 1280; m0 = (t2 >> 3) * 128; n0 = (t2 & 7) * 128; Bt = Wqt; }
    else    { m0 = (id >> 4) * 128; n0 = (id & 15) * 128; Bt = Wkt; }
    const int wr = (w >> 1) * 64, wc = (w & 1) * 64;

    const int sr0 = w * 32 + (lane >> 2), sr1 = sr0 + 16;
    const int cg  = (lane & 3) ^ ((lane >> 4) & 3);
    u16* abase = As + w * 1024;
    u16* bbase = Bs + w * 1024;

    const u16 *ar0, *ar1;
    {
        int g0 = m0 + sr0, g1 = m0 + sr1;
        if (qm) {
            ar0 = A + ((size_t)(g0 >> 10) * 5120 + (g0 & 1023)) * 1024;
            ar1 = A + ((size_t)(g1 >> 10) * 5120 + (g1 & 1023)) * 1024;
        } else {
            ar0 = A + (size_t)g0 * 1024;
            ar1 = A + (size_t)g1 * 1024;
        }
        ar0 += cg * 8; ar1 += cg * 8;
    }
    const u16* br0 = Bt + (size_t)(n0 + sr0) * 1024 + cg * 8;
    const u16* br1 = Bt + (size_t)(n0 + sr1) * 1024 + cg * 8;

    f32x4 acc[4][4] = {};
    const int sel = (quad ^ (l16 >> 2)) * 8;

    for (int k0 = 0; k0 < 1024; k0 += 32) {
        async16(ar0 + k0, abase);
        async16(ar1 + k0, abase + 512);
        async16(br0 + k0, bbase);
        async16(br1 + k0, bbase + 512);
        __syncthreads();

        bf16x8 av[4], bv[4];
#pragma unroll
        for (int i = 0; i < 4; ++i)
            av[i] = *(const bf16x8*)&As[(wr + i * 16 + l16) * 32 + sel];
#pragma unroll
        for (int j = 0; j < 4; ++j)
            bv[j] = *(const bf16x8*)&Bs[(wc + j * 16 + l16) * 32 + sel];
#pragma unroll
        for (int i = 0; i < 4; ++i)
#pragma unroll
            for (int j = 0; j < 4; ++j)
                acc[i][j] = __builtin_amdgcn_mfma_f32_16x16x32_bf16(av[i], bv[j], acc[i][j], 0, 0, 0);
        __syncthreads();
    }

    // Epilogue. C/D layout: col=lane&15, row=quad*4+reg.
    if (qm) {
        const float SC = 0.180336880f;   // 0.125 * log2(e) folded into q
#pragma unroll
        for (int j = 0; j < 4; ++j) {
            int col = n0 + wc + j * 16 + l16;
#pragma unroll
            for (int i = 0; i < 4; ++i) {
                int rowb = m0 + wr + i * 16 + quad * 4;
#pragma unroll
                for (int r = 0; r < 4; ++r)
                    q[(size_t)(rowb + r) * 1024 + col] = f2bf(acc[i][j][r] * SC);
            }
        }
        return;
    }
    int b = m0 >= 5120;
    int keyb = m0 - b * 5120;
    if (n0 < 1024) {
        // K: direct stores (32-B runs per key row)
#pragma unroll
        for (int j = 0; j < 4; ++j) {
            int col = n0 + wc + j * 16 + l16;
#pragma unroll
            for (int i = 0; i < 4; ++i) {
                int rowb = m0 + wr + i * 16 + quad * 4;
                int key = rowb - b * 5120;
                int bh = b * 16 + (col >> 6), d = col & 63;
                u16* dst = Kh + ((size_t)bh * 5120 + key) * 64 + d;
#pragma unroll
                for (int r = 0; r < 4; ++r) dst[r * 64] = f2bf(acc[i][j][r]);
            }
        }
    } else {
        // V: restage through LDS -> fully coalesced Vh[bh][d][key] writes
        u16* T = smem;   // [128][136]
#pragma unroll
        for (int j = 0; j < 4; ++j) {
            int d2 = wc + j * 16 + l16;
#pragma unroll
            for (int i = 0; i < 4; ++i) {
                int kl = wr + i * 16 + quad * 4;
                union { u16 a[4]; uint2 v; } pk;
#pragma unroll
                for (int r = 0; r < 4; ++r) pk.a[r] = f2bf(acc[i][j][r]);
                *(uint2*)&T[d2 * 136 + kl] = pk.v;
            }
        }
        __syncthreads();
        int hb = (n0 - 1024) >> 6;
#pragma unroll
        for (int p = 0; p < 8; ++p) {
            int idx = p * 256 + t;
            int d2 = idx >> 4, k0c = (idx & 15) * 8;
            uint4 vv = *(const uint4*)&T[d2 * 136 + k0c];
            int bh = b * 16 + hb + (d2 >> 6), d = d2 & 63;
            *(uint4*)(Vh + ((size_t)bh * 64 + d) * 5120 + keyb + k0c) = vv;
        }
    }
}

// ---------------------------------------------------------------------------
// Out-proj GEMM: out[2048,1024] fp32 = ao @ Wpt^T + bias. 128x64 tile.
// ---------------------------------------------------------------------------
__global__ __launch_bounds__(256, 2)
void gemm_proj(const u16* __restrict__ A, const u16* __restrict__ Bt,
               const float* __restrict__ bias, float* __restrict__ Cf)
{
    __shared__ __align__(16) u16 As[128 * 32];
    __shared__ __align__(16) u16 Bs[64 * 32];

    const int t = threadIdx.x, w = t >> 6;
    const int lane = t & 63, quad = lane >> 4, l16 = lane & 15;
    const int m0 = blockIdx.y * 128, n0 = blockIdx.x * 64;
    const int wr = w * 32;

    const int sr0 = w * 32 + (lane >> 2), sr1 = sr0 + 16;
    const int cg  = (lane & 3) ^ ((lane >> 4) & 3);
    u16* abase = As + w * 1024;
    u16* bbase = Bs + w * 512;

    const u16* ar0 = A + (size_t)(m0 + sr0) * 1024 + cg * 8;
    const u16* ar1 = A + (size_t)(m0 + sr1) * 1024 + cg * 8;
    const u16* br0 = Bt + (size_t)(n0 + w * 16 + (lane >> 2)) * 1024 + cg * 8;

    f32x4 acc[2][4] = {};
    const int sel = (quad ^ (l16 >> 2)) * 8;

    for (int k0 = 0; k0 < 1024; k0 += 32) {
        async16(ar0 + k0, abase);
        async16(ar1 + k0, abase + 512);
        async16(br0 + k0, bbase);
        __syncthreads();

        bf16x8 av[2], bv[4];
#pragma unroll
        for (int i = 0; i < 2; ++i)
            av[i] = *(const bf16x8*)&As[(wr + i * 16 + l16) * 32 + sel];
#pragma unroll
        for (int j = 0; j < 4; ++j)
            bv[j] = *(const bf16x8*)&Bs[(j * 16 + l16) * 32 + sel];
#pragma unroll
        for (int i = 0; i < 2; ++i)
#pragma unroll
            for (int j = 0; j < 4; ++j)
                acc[i][j] = __builtin_amdgcn_mfma_f32_16x16x32_bf16(av[i], bv[j], acc[i][j], 0, 0, 0);
        __syncthreads();
    }

#pragma unroll
    for (int j = 0; j < 4; ++j) {
        int col = n0 + j * 16 + l16;
        float bvl = bias[col];
#pragma unroll
        for (int i = 0; i < 2; ++i) {
            int rowb = m0 + wr + i * 16 + quad * 4;
#pragma unroll
            for (int r = 0; r < 4; ++r)
                Cf[(size_t)(rowb + r) * 1024 + col] = acc[i][j][r] + bvl;
        }
    }
}

// ---------------------------------------------------------------------------
// Split-K flash attention (R9 post-mortem: grid 1280 with 4 resident blocks
// per CU left a 1-block tail per CU at 1/4 occupancy -- makespan ~2x the
// full-occupancy phase; OccupancyPercent 31% = avg(50%,12.5%) confirms).
// THIS ROUND: 4 parts x 1280 keys (20 chunks) -> grid 1024 = EXACTLY 4
// blocks/CU, zero tail. Same total chunk-work per CU (80 block-chunks).
// R9 machinery unchanged: interleaved-key K layout (no V transpose), K+V
// via global_load_lds w/ pre-swizzled source, dbuf both, 1 barrier/chunk.
// ---------------------------------------------------------------------------
__global__ __launch_bounds__(256, 4)
void attn_k(const u16* __restrict__ Q, const u16* __restrict__ Kh,
            const u16* __restrict__ Vh, u16* __restrict__ Op,
            float* __restrict__ Lp)
{
    __shared__ __align__(16) u16 Ks[2][4096]; // [buf][row64][slot8^(row&7)][8]
    __shared__ __align__(16) u16 Vt[2][4096]; // [buf][d64][slot8^(d&7)][8]
    __shared__ __align__(16) u16 Ps[4096];    // [wave][row16][slot8^(row&7)][8]

    const int tid  = threadIdx.x;
    const int wave = tid >> 6, lane = tid & 63;
    const int quad = lane >> 4, l16 = lane & 15;
    const int bx = blockIdx.x;
    const int x   = bx & 7;                  // XCD slot (round-robin dispatch)
    const int seq = bx >> 3;                 // 0..127 per-XCD sequence
    const int qt  = seq & 7;
    const int kg  = seq >> 3;                // 0..15
    const int g   = x + 8 * kg;              // group = (part, bh), 0..127
    const int part = g >> 5;                 // 0..3 (1280 keys each)
    const int bh   = g & 31;
    const int h = bh & 15, b = bh >> 4;

    const int qrow0 = b * 1024 + qt * 128 + wave * 32;
    const u16* qbase = Q + (size_t)qrow0 * 1024 + h * 64;

    bf16x8 aq[2][2];
#pragma unroll
    for (int rt = 0; rt < 2; ++rt) {
        aq[rt][0] = *(const bf16x8*)(qbase + (size_t)(rt * 16 + l16) * 1024 +      quad * 8);
        aq[rt][1] = *(const bf16x8*)(qbase + (size_t)(rt * 16 + l16) * 1024 + 32 + quad * 8);
    }

    union { u32 u[4]; bf16x8 v; } onesf;
#pragma unroll
    for (int i = 0; i < 4; ++i) onesf.u[i] = 0x3F803F80u;

    f32x4 o[2][4] = {};
    f32x4 lacc[2] = {};

    const u16* kbase = Kh + (size_t)bh * 5120 * 64;
    const u16* vbase = Vh + (size_t)bh * 64 * 5120;
    const int l7 = l16 & 7;
    u16* psw = Ps + wave * 1024;
    const int m_beg = part * 1280;

    // Async staging geometry (per thread): LDS row r1 = tid>>3 (first half)
    // and 32+r1 (second half); phys slot sl = tid&7; logical slot sl^(r1&7).
    const int r1 = tid >> 3;
    const int sl = tid & 7;
    const int xs = sl ^ (r1 & 7);
    // K: LDS row r holds key kappa(r); kappa(r1) = 2*r1, kappa(32+r1) = 2*r1+1.
    const u16* kga = kbase + (size_t)(m_beg + 2 * r1) * 64 + xs * 8;
    // V: natural key order; row d = r1 / 32+r1.
    const u16* vga = vbase + (size_t)r1 * 5120 + m_beg + xs * 8;
    u16* kldsw = &Ks[0][0] + wave * 512;     // + lane*16B implicit
    u16* vldsw = &Vt[0][0] + wave * 512;

    // Prologue: chunk 0 into buffer 0 (latency exposed once).
    async16(kga,              kldsw);
    async16(kga + 64,         kldsw + 2048);          // key +1 (row 32+r1)
    async16(vga,              vldsw);
    async16(vga + 32 * 5120,  vldsw + 2048);          // d +32

    for (int c = 0; c < 20; ++c) {
        __syncthreads();   // drain own asyncs for chunk c; all buffers ready

        // Issue chunk c+1 into the other buffer; full compute phase hides it.
        if (c < 19) {
            const int nb = (c + 1) & 1;
            const u16* ka = kga + (size_t)(c + 1) * 4096;   // +64 keys
            const u16* va = vga + (c + 1) * 64;             // +64 keys
            u16* kd = &Ks[nb][0] + wave * 512;
            u16* vd = &Vt[nb][0] + wave * 512;
            async16(ka,             kd);
            async16(ka + 64,        kd + 2048);
            async16(va,             vd);
            async16(va + 32 * 5120, vd + 2048);
        }

        const u16* KsC = &Ks[c & 1][0];
        const u16* VtC = &Vt[c & 1][0];

        f32x4 s[2][4] = {};
        __builtin_amdgcn_s_setprio(1);
#pragma unroll
        for (int nt = 0; nt < 4; ++nt) {
            const u16* krow = KsC + (nt * 16 + l16) * 64;
            bf16x8 kb0 = *(const bf16x8*)(krow + ((quad     ^ l7) * 8));
            bf16x8 kb1 = *(const bf16x8*)(krow + (((4+quad) ^ l7) * 8));
#pragma unroll
            for (int rt = 0; rt < 2; ++rt) {
                s[rt][nt] = __builtin_amdgcn_mfma_f32_16x16x32_bf16(aq[rt][0], kb0, s[rt][nt], 0, 0, 0);
                s[rt][nt] = __builtin_amdgcn_mfma_f32_16x16x32_bf16(aq[rt][1], kb1, s[rt][nt], 0, 0, 0);
            }
        }
        __builtin_amdgcn_s_setprio(0);

        // Per-rt: softmax -> P (natural key order) -> l,PV.
        // Lane holds keys: s[rt][0]=2*l16, s[rt][2]=2*l16+1 (pair @ word l16&3,
        // slot l16>>2), s[rt][1]=32+2*l16, s[rt][3]=33+2*l16 (slot 4+(l16>>2)).
#pragma unroll
        for (int rt = 0; rt < 2; ++rt) {
#pragma unroll
            for (int r = 0; r < 4; ++r) {
                float e0 = exp2f(s[rt][0][r]);
                float e1 = exp2f(s[rt][1][r]);
                float e2 = exp2f(s[rt][2][r]);
                float e3 = exp2f(s[rt][3][r]);
                u32 pwx = __builtin_amdgcn_perm(fbits(e2), fbits(e0), 0x07060302u);
                u32 pwy = __builtin_amdgcn_perm(fbits(e3), fbits(e1), 0x07060302u);
                int qr = quad * 4 + r;
                u16* prow = psw + qr * 64;
                *(u32*)(prow + ((( (l16 >> 2)    ) ^ (qr & 7)) * 8) + (l16 & 3) * 2) = pwx;
                *(u32*)(prow + ((( (l16 >> 2) + 4) ^ (qr & 7)) * 8) + (l16 & 3) * 2) = pwy;
            }

            asm volatile("s_waitcnt lgkmcnt(0)" ::: "memory");

            const u16* prow = psw + l16 * 64;
            bf16x8 pf0 = *(const bf16x8*)(prow + ((quad     ^ l7) * 8));
            bf16x8 pf1 = *(const bf16x8*)(prow + (((4+quad) ^ l7) * 8));

            __builtin_amdgcn_s_setprio(1);
            lacc[rt] = __builtin_amdgcn_mfma_f32_16x16x32_bf16(pf0, onesf.v, lacc[rt], 0, 0, 0);
            lacc[rt] = __builtin_amdgcn_mfma_f32_16x16x32_bf16(pf1, onesf.v, lacc[rt], 0, 0, 0);
#pragma unroll
            for (int dt = 0; dt < 4; ++dt) {
                const u16* vrow = VtC + (dt * 16 + l16) * 64;
                bf16x8 v0 = *(const bf16x8*)(vrow + ((quad     ^ l7) * 8));
                bf16x8 v1 = *(const bf16x8*)(vrow + (((4+quad) ^ l7) * 8));
                o[rt][dt] = __builtin_amdgcn_mfma_f32_16x16x32_bf16(pf0, v0, o[rt][dt], 0, 0, 0);
                o[rt][dt] = __builtin_amdgcn_mfma_f32_16x16x32_bf16(pf1, v1, o[rt][dt], 0, 0, 0);
            }
            __builtin_amdgcn_s_setprio(0);
        }
        // no end barrier: next chunk writes the other Ks/Vt buffer; Ps is
        // per-wave and per-wave DS ops are in-order.
    }

    const int Rb = bh * 1024 + qt * 128 + wave * 32;
    u16* obase = Op + ((size_t)part << 21);
#pragma unroll
    for (int rt = 0; rt < 2; ++rt)
#pragma unroll
        for (int dt = 0; dt < 4; ++dt)
#pragma unroll
            for (int r = 0; r < 4; ++r) {
                int R = Rb + rt * 16 + quad * 4 + r;
                obase[(size_t)R * 64 + dt * 16 + l16] = f2bf(o[rt][dt][r]);
            }
    if (l16 == 0) {
#pragma unroll
        for (int rt = 0; rt < 2; ++rt)
#pragma unroll
            for (int r = 0; r < 4; ++r)
                Lp[part * 32768 + Rb + rt * 16 + quad * 4 + r] = lacc[rt][r];
    }
}

// ---------------------------------------------------------------------------
// Combine: ao[b,n,h*64+d] = (sum_p Op[p]) / (sum_p Lp[p]).  4 parts.
// ---------------------------------------------------------------------------
__global__ void comb_k(const u16* __restrict__ Op, const float* __restrict__ Lp,
                       u16* __restrict__ ao)
{
    int t = blockIdx.x * 256 + threadIdx.x;
    int R = t >> 4, dg = (t & 15) * 4;
    float l = Lp[R] + Lp[32768 + R] + Lp[65536 + R] + Lp[98304 + R];
    float a[4] = {0.f, 0.f, 0.f, 0.f};
#pragma unroll
    for (int p = 0; p < 4; ++p) {
        union { u16 a[4]; uint2 v; } w;
        w.v = *(const uint2*)(Op + ((size_t)p << 21) + (size_t)R * 64 + dg);
#pragma unroll
        for (int j = 0; j < 4; ++j) a[j] += bf2f(w.a[j]);
    }
    float inv = 1.f / l;
    int bh = R >> 10, n = R & 1023, b = bh >> 4, h = bh & 15;
    union { u16 a[4]; uint2 v; } out;
#pragma unroll
    for (int j = 0; j < 4; ++j) out.a[j] = f2bf(a[j] * inv);
    *(uint2*)(ao + (size_t)(b * 1024 + n) * 1024 + h * 64 + dg) = out.v;
}

// ---------------------------------------------------------------------------
// Workspace map (4 parts): Op [4,20M) fully inside dead Xc; Lp [24,24.5M)
// in dead Wkt half; Wpt [26,28M) untouched.
// ---------------------------------------------------------------------------
extern "C" void kernel_launch(void* const* d_in, const int* in_sizes, int n_in,
                              void* d_out, int out_size, void* d_ws, size_t ws_size,
                              hipStream_t stream)
{
    const float* x_obj = (const float*)d_in[0];
    const float* x_ctx = (const float*)d_in[1];
    const float* Wq    = (const float*)d_in[2];
    const float* Wkv   = (const float*)d_in[3];
    const float* Wproj = (const float*)d_in[4];
    const float* bproj = (const float*)d_in[5];
    float* out = (float*)d_out;                   // [2,1024,1024] fp32

    u16* Xc  = (u16*)d_ws;                        // [10240][1024]   20 MB
    u16* ao  = Xc;                                // alias (attn out, 4 MB)
    u16* Op  = Xc + (size_t)2097152;              // alias (partials, 16 MB)
    u16* Wqt = Xc  + (size_t)10485760;            // 2 MB
    u16* Wkt = Wqt + (size_t)1048576;             // 4 MB
    u16* Wpt = Wkt + (size_t)2097152;             // 2 MB
    u16* q   = Wpt + (size_t)1048576;             // 4 MB
    u16* Kh  = q   + (size_t)2097152;             // [32][5120][64] 20 MB
    u16* Vh  = Kh  + (size_t)10485760;            // [32][64][5120] 20 MB
    float* Lp = (float*)(Wkt + (size_t)1048576);  // [4][32768] in dead Wkt half

    dim3 blk(256);
    cvt_all_k<<<dim3(11264), blk, 0, stream>>>(x_obj, x_ctx, Xc,
                                               Wq, Wkv, Wproj, Wqt, Wkt, Wpt);
    gemm_qkv<<<dim3(1408), blk, 0, stream>>>(Xc, Wqt, Wkt, q, Kh, Vh);
    attn_k<<<dim3(1024), blk, 0, stream>>>(q, Kh, Vh, Op, Lp);
    comb_k<<<dim3(2048), blk, 0, stream>>>(Op, Lp, ao);
    gemm_proj<<<dim3(16, 16), blk, 0, stream>>>(ao, Wpt, bproj, out);
}